// Round 8
// baseline (742.794 us; speedup 1.0000x reference)
//
#include <hip/hip_runtime.h>
#include <hip/hip_cooperative_groups.h>
#include <math.h>

namespace cg = cooperative_groups;

// Problem constants
#define BB 2
#define TT 2048
#define DD 1024
#define HH 16
#define DH 64
#define BT (BB*TT)          // 4096
#define CC 64               // chunk length
#define NC (TT/CC)          // 32 chunks
#define EPSV 1e-6f
#define QS 3072             // fused qkv row stride (bf16)

typedef __attribute__((ext_vector_type(8))) short short8;
typedef __attribute__((ext_vector_type(4))) float f32x4;

__device__ inline ushort f2bf(float f) {
    unsigned u = __float_as_uint(f);
    u = (u + 0x7fffu + ((u >> 16) & 1u)) >> 16;   // RNE
    return (ushort)u;
}
__device__ inline float bf2f(ushort u) {
    return __uint_as_float(((unsigned)u) << 16);
}

__device__ inline void async16(const void* g, void* l) {
    __builtin_amdgcn_global_load_lds(
        (const __attribute__((address_space(1))) void*)g,
        (__attribute__((address_space(3))) void*)l, 16, 0, 0);
}

// ---------------------------------------------------------------------------
// Pack fp32 -> bf16: xb (4M), Wqkvb = [Wq;Wk;Wv] (3M), Wob (1M); biasq fp32.
// ---------------------------------------------------------------------------
__global__ __launch_bounds__(256) void convert_pack(
    const float* __restrict__ x, const float* __restrict__ Wq,
    const float* __restrict__ Wk, const float* __restrict__ Wv,
    const float* __restrict__ Wo, const float* __restrict__ bq,
    const float* __restrict__ bk, const float* __restrict__ bv,
    ushort* __restrict__ xb, ushort* __restrict__ Wqkvb,
    ushort* __restrict__ Wob, float* __restrict__ biasq)
{
    int i = blockIdx.x * 256 + threadIdx.x;      // 0..1048575
    int idx = i * 8;
    const float* src;
    ushort* dst;
    if (idx < 4194304) { src = x + idx; dst = xb + idx; }
    else if (idx < 7340032) {
        int r = idx - 4194304;
        int w = r >> 20;
        int o = r & 1048575;
        src = (w == 0 ? Wq : (w == 1 ? Wk : Wv)) + o;
        dst = Wqkvb + r;
    } else {
        int r = idx - 7340032;
        src = Wo + r; dst = Wob + r;
    }
    float4 f0 = *(const float4*)src;
    float4 f1 = *(const float4*)(src + 4);
    *(ushort4*)dst = make_ushort4(f2bf(f0.x), f2bf(f0.y), f2bf(f0.z), f2bf(f0.w));
    *(ushort4*)(dst + 4) = make_ushort4(f2bf(f1.x), f2bf(f1.y), f2bf(f1.z), f2bf(f1.w));
    if (i < 3072)
        biasq[i] = (i < 1024) ? bq[i] : (i < 2048) ? bk[i - 1024] : bv[i - 2048];
}

// ---------------------------------------------------------------------------
// MFMA bf16 GEMM, BK=64: C = act(A·Wᵀ + bias).
// m-tile on blockIdx.x so blk%8 (XCD) ties to m -> activation rows L2-local.
// OBF16: bf16 out via LDS transpose; else fp32 out via LDS-staged float4.
// ---------------------------------------------------------------------------
template<int TBM, int TBN, bool OBF16>
__global__ __launch_bounds__(256) void gemm_mfma(
    const ushort* __restrict__ A, const ushort* __restrict__ W,
    const float* __restrict__ bias, void* __restrict__ Cv,
    int M, int N, int K, int act_limit)
{
    constexpr int IT = TBM / 32, JT = TBN / 32;
    constexpr int APT = TBM * 8 / 256;
    constexpr int BPT = TBN * 8 / 256;
    constexpr int STAGE_US = (TBM + TBN) * 64;
    constexpr int EPI_US = OBF16 ? TBM * 132 : TBM * 264;
    constexpr int SMEM_US = (EPI_US > STAGE_US) ? EPI_US : STAGE_US;
    __shared__ __align__(16) ushort smem[SMEM_US];
    ushort* As = smem;
    ushort* Bs = smem + TBM * 64;
    int tid = threadIdx.x;
    int lane = tid & 63, wave = tid >> 6;
    int m0 = blockIdx.x * TBM, n0 = blockIdx.y * TBN;
    int wm = (wave >> 1) * (TBM / 2), wn = (wave & 1) * (TBN / 2);

    const ushort* gA[APT]; ushort* lA[APT];
    const ushort* gB[BPT]; ushort* lB[BPT];
#pragma unroll
    for (int s = 0; s < APT; s++) {
        int slot = s * 256 + tid;
        int row = slot >> 3, p = slot & 7, kg = p ^ (row & 7);
        gA[s] = A + (size_t)(m0 + row) * K + kg * 8;
        lA[s] = &As[slot * 8];
    }
#pragma unroll
    for (int s = 0; s < BPT; s++) {
        int slot = s * 256 + tid;
        int row = slot >> 3, p = slot & 7, kg = p ^ (row & 7);
        gB[s] = W + (size_t)(n0 + row) * K + kg * 8;
        lB[s] = &Bs[slot * 8];
    }

    int fr = lane & 15, g = lane >> 4;

    f32x4 acc[IT][JT];
#pragma unroll
    for (int i = 0; i < IT; i++)
#pragma unroll
        for (int j = 0; j < JT; j++) acc[i][j] = (f32x4){0.f, 0.f, 0.f, 0.f};

    for (int kt = 0; kt < K; kt += 64) {
#pragma unroll
        for (int s = 0; s < APT; s++) async16(gA[s] + kt, lA[s]);
#pragma unroll
        for (int s = 0; s < BPT; s++) async16(gB[s] + kt, lB[s]);
        __syncthreads();
#pragma unroll
        for (int ks = 0; ks < 2; ks++) {
            int kg = ks * 4 + g;
            short8 af[IT], bf[JT];
#pragma unroll
            for (int i = 0; i < IT; i++) {
                int mr = wm + i * 16 + fr;
                af[i] = *(const short8*)&As[mr * 64 + (kg ^ (mr & 7)) * 8];
            }
#pragma unroll
            for (int j = 0; j < JT; j++) {
                int nr = wn + j * 16 + fr;
                bf[j] = *(const short8*)&Bs[nr * 64 + (kg ^ (nr & 7)) * 8];
            }
#pragma unroll
            for (int i = 0; i < IT; i++)
#pragma unroll
                for (int j = 0; j < JT; j++)
                    acc[i][j] = __builtin_amdgcn_mfma_f32_16x16x32_bf16(
                        af[i], bf[j], acc[i][j], 0, 0, 0);
        }
        __syncthreads();
    }

    // epilogue: C/D layout col=lane&15, row=(lane>>4)*4+reg
    if (OBF16) {
        ushort* Cs = smem;   // TBM x 132
#pragma unroll
        for (int j = 0; j < JT; j++) {
            int colL = wn + j * 16 + fr;
            float bv_ = bias[n0 + colL];
            bool act = (n0 + colL) < act_limit;
#pragma unroll
            for (int i = 0; i < IT; i++) {
                int rowL = wm + i * 16 + g * 4;
#pragma unroll
                for (int r = 0; r < 4; r++) {
                    float v = acc[i][j][r] + bv_;
                    if (act) v = (v > 0.f) ? (v + 1.f) : expf(v);
                    Cs[(rowL + r) * 132 + colL] = f2bf(v);
                }
            }
        }
        __syncthreads();
        ushort* C = (ushort*)Cv;
        int orow = tid >> 4, ocol = (tid & 15) * 8;
#pragma unroll
        for (int it = 0; it < TBM / 16; it++) {
            int rr = orow + it * 16;
            ushort4 lo = *(const ushort4*)&Cs[rr * 132 + ocol];
            ushort4 hi = *(const ushort4*)&Cs[rr * 132 + ocol + 4];
            ushort pk8[8] = {lo.x, lo.y, lo.z, lo.w, hi.x, hi.y, hi.z, hi.w};
            *(uint4*)&C[(size_t)(m0 + rr) * N + n0 + ocol] = *(uint4*)pk8;
        }
    } else {
        float* Cs = (float*)smem;   // TBM x 132 fp32
#pragma unroll
        for (int j = 0; j < JT; j++) {
            int colL = wn + j * 16 + fr;
            float bv_ = bias[n0 + colL];
            bool act = (n0 + colL) < act_limit;
#pragma unroll
            for (int i = 0; i < IT; i++) {
                int rowL = wm + i * 16 + g * 4;
#pragma unroll
                for (int r = 0; r < 4; r++) {
                    float v = acc[i][j][r] + bv_;
                    if (act) v = (v > 0.f) ? (v + 1.f) : expf(v);
                    Cs[(rowL + r) * 132 + colL] = v;
                }
            }
        }
        __syncthreads();
        float* C = (float*)Cv;
#pragma unroll
        for (int it = 0; it < TBM * TBN / 1024; it++) {
            int slot = it * 256 + tid;
            int row = slot / (TBN / 4), c4 = slot % (TBN / 4);
            float4 v4 = *(const float4*)&Cs[row * 132 + c4 * 4];
            *(float4*)&C[(size_t)(m0 + row) * N + n0 + c4 * 4] = v4;
        }
    }
}

// ===========================================================================
// Middle phase bodies, shared by the fused cooperative kernel and the
// 3-kernel fallback path. LDS (ushort idx): R0 @0: KT ph1 / Q ph3.
// R1 @4096: K rows, P in ph3. R2 @8192 (5120): SpT ph3 then O-stage.
// R3 @13312 (5120): VT. 8-quad XOR swizzle throughout.
// ===========================================================================
#define LQ_ 0
#define LK_ 4096
#define LSP_ 8192
#define LVT_ 13312

__device__ __forceinline__ void mid_phase1(
    const ushort* __restrict__ qkv, ushort* __restrict__ Sb,
    int blk, ushort* sm)
{
    int tid = threadIdx.x, lane = tid & 63, wave = tid >> 6;
    int c = blk & (NC - 1);
    int bh = blk >> 5;
    int b = bh >> 4, h = bh & 15;
    size_t rowbase = (size_t)(b * TT + c * CC) * QS + h * DH;
    int fr = lane & 15, g = lane >> 4;

    // stage K rows (async, swizzled), KT + VT (scatter)
#pragma unroll
    for (int r = 0; r < 2; r++) {
        int slot = (r * 4 + wave) * 64 + lane;
        int row = slot >> 3, p = slot & 7;
        int kg = p ^ (row & 7);
        async16(qkv + rowbase + (size_t)row * QS + 1024 + kg * 8, &sm[LK_ + slot * 8]);
    }
    {
        int rrow = tid >> 4, rc4 = (tid & 15) * 4;
#pragma unroll
        for (int r = 0; r < 4; r++) {
            int row = rrow + r * 16;
            ushort4 k4 = *(const ushort4*)&qkv[rowbase + (size_t)row * QS + 1024 + rc4];
            ushort4 v4 = *(const ushort4*)&qkv[rowbase + (size_t)row * QS + 2048 + rc4];
#pragma unroll
            for (int j = 0; j < 4; j++) {
                int d = rc4 + j;
                int pos = (row >> 3) ^ (d & 7);
                sm[LQ_  + d * 64 + pos * 8 + (row & 7)] = ((const ushort*)&k4)[j];
                sm[LVT_ + d * 64 + pos * 8 + (row & 7)] = ((const ushort*)&v4)[j];
            }
        }
        if (tid < 16) {   // ones row e=64 of VT
            ushort4 one4 = make_ushort4(0x3F80, 0x3F80, 0x3F80, 0x3F80);
            *(ushort4*)&sm[LVT_ + 64 * 64 + tid * 4] = one4;
        }
    }
    __syncthreads();

    // Sᵀ_ext[e][d] = Σ_t V_ext[t][e]·K[t][d]
    short8 bk_[2];
#pragma unroll
    for (int kt = 0; kt < 2; kt++) {
        int row = wave * 16 + fr;
        int kg = kt * 4 + g;
        bk_[kt] = *(const short8*)&sm[LQ_ + row * 64 + (kg ^ (row & 7)) * 8];
    }
    f32x4 accS[5];
#pragma unroll
    for (int it = 0; it < 5; it++) accS[it] = (f32x4){0.f, 0.f, 0.f, 0.f};
#pragma unroll
    for (int it = 0; it < 5; it++) {
        int arow = it * 16 + fr;
#pragma unroll
        for (int kt = 0; kt < 2; kt++) {
            int kg = kt * 4 + g;
            short8 av = *(const short8*)&sm[LVT_ + arow * 64 + (kg ^ (arow & 7)) * 8];
            accS[it] = __builtin_amdgcn_mfma_f32_16x16x32_bf16(av, bk_[kt], accS[it], 0, 0, 0);
        }
    }
    size_t sb = (size_t)blk * 5120;
#pragma unroll
    for (int it = 0; it < 4; it++)
#pragma unroll
        for (int r = 0; r < 4; r++) {
            int e = it * 16 + g * 4 + r;
            Sb[sb + e * 64 + wave * 16 + fr] = f2bf(accS[it][r]);
        }
    if (g == 0) Sb[sb + 64 * 64 + wave * 16 + fr] = f2bf(accS[4][0]);
}

__device__ __forceinline__ void mid_phase2(
    const ushort* __restrict__ Sb, ushort* __restrict__ SpT, int blk)
{
    int tid = threadIdx.x;
    int pbh = blk >> 5, seg = blk & 31;       // 32 bh x 32 segs of 160
    size_t base = (size_t)pbh * NC * 5120;
    if (tid >= 160) return;
    int idx = seg * 160 + tid;                // 0..5119
    int e = idx >> 6, d = idx & 63;
    int pos = (d >> 3) ^ (e & 7);
    size_t woff = (size_t)e * 64 + pos * 8 + (d & 7);
    if (e <= 64) {
        float run = 0.f;
        for (int cc = 0; cc < NC; cc++) {
            size_t boff = base + (size_t)cc * 5120;
            float t = bf2f(Sb[boff + idx]);
            SpT[boff + woff] = f2bf(run);
            run += t;
        }
    } else {
        for (int cc = 0; cc < NC; cc++)
            SpT[base + (size_t)cc * 5120 + woff] = 0;
    }
}

template<bool STAGE_KV>
__device__ __forceinline__ void mid_phase3(
    const ushort* __restrict__ qkv, const ushort* __restrict__ SpT,
    ushort* __restrict__ ob, int blk, ushort* sm)
{
    int tid = threadIdx.x, lane = tid & 63, wave = tid >> 6;
    int c = blk & (NC - 1);
    int bh = blk >> 5;
    int b = bh >> 4, h = bh & 15;
    size_t rowbase = (size_t)(b * TT + c * CC) * QS + h * DH;
    int fr = lane & 15, g = lane >> 4;

    // stage Q (and K rows if standalone)
#pragma unroll
    for (int r = 0; r < 2; r++) {
        int slot = (r * 4 + wave) * 64 + lane;
        int row = slot >> 3, p = slot & 7;
        int kg = p ^ (row & 7);
        const ushort* gq = qkv + rowbase + (size_t)row * QS + kg * 8;
        async16(gq, &sm[LQ_ + slot * 8]);
        if (STAGE_KV) async16(gq + 1024, &sm[LK_ + slot * 8]);
    }
    // stage SpT (pre-swizzled in global): flat copy, 640 slots
    {
        size_t spbase = (size_t)blk * 5120;
        int slot = wave * 64 + lane;
        async16(SpT + spbase + slot * 8, &sm[LSP_ + slot * 8]);
        async16(SpT + spbase + (slot + 256) * 8, &sm[LSP_ + (slot + 256) * 8]);
        if (wave < 2) {
            int s2 = 512 + wave * 64 + lane;
            async16(SpT + spbase + s2 * 8, &sm[LSP_ + s2 * 8]);
        }
    }
    if (STAGE_KV) {
        int rrow = tid >> 4, rc4 = (tid & 15) * 4;
#pragma unroll
        for (int r = 0; r < 4; r++) {
            int row = rrow + r * 16;
            ushort4 v4 = *(const ushort4*)&qkv[rowbase + (size_t)row * QS + 2048 + rc4];
#pragma unroll
            for (int j = 0; j < 4; j++) {
                int e = rc4 + j;
                int pos = (row >> 3) ^ (e & 7);
                sm[LVT_ + e * 64 + pos * 8 + (row & 7)] = ((const ushort*)&v4)[j];
            }
        }
        if (tid < 16) {
            ushort4 one4 = make_ushort4(0x3F80, 0x3F80, 0x3F80, 0x3F80);
            *(ushort4*)&sm[LVT_ + 64 * 64 + tid * 4] = one4;
        }
    }
    __syncthreads();

    int mrow = wave * 16 + fr;
    short8 aq[2];
#pragma unroll
    for (int kt = 0; kt < 2; kt++) {
        int kg = kt * 4 + g;
        aq[kt] = *(const short8*)&sm[LQ_ + mrow * 64 + (kg ^ (mrow & 7)) * 8];
    }

    // Step A: A = Q·Kᵀ
    f32x4 accA[4];
#pragma unroll
    for (int jt = 0; jt < 4; jt++) accA[jt] = (f32x4){0.f, 0.f, 0.f, 0.f};
#pragma unroll
    for (int jt = 0; jt < 4; jt++) {
        int nrow = jt * 16 + fr;
#pragma unroll
        for (int kt = 0; kt < 2; kt++) {
            int kg = kt * 4 + g;
            short8 bk_ = *(const short8*)&sm[LK_ + nrow * 64 + (kg ^ (nrow & 7)) * 8];
            accA[jt] = __builtin_amdgcn_mfma_f32_16x16x32_bf16(aq[kt], bk_, accA[jt], 0, 0, 0);
        }
    }
    __syncthreads();

    // mask -> P (bf16) into LK region
#pragma unroll
    for (int jt = 0; jt < 4; jt++) {
        int s = jt * 16 + fr;
#pragma unroll
        for (int r = 0; r < 4; r++) {
            int t = wave * 16 + g * 4 + r;
            float pv = (s <= t) ? accA[jt][r] : 0.f;
            int pos = (s >> 3) ^ (t & 7);
            sm[LK_ + t * 64 + pos * 8 + (s & 7)] = f2bf(pv);
        }
    }

    // Step B: O += Q·Sp_ext
    f32x4 acc[5];
#pragma unroll
    for (int jt = 0; jt < 5; jt++) acc[jt] = (f32x4){0.f, 0.f, 0.f, 0.f};
#pragma unroll
    for (int jt = 0; jt < 5; jt++) {
        int nrow = jt * 16 + fr;
#pragma unroll
        for (int kt = 0; kt < 2; kt++) {
            int kg = kt * 4 + g;
            short8 bsp = *(const short8*)&sm[LSP_ + nrow * 64 + (kg ^ (nrow & 7)) * 8];
            acc[jt] = __builtin_amdgcn_mfma_f32_16x16x32_bf16(aq[kt], bsp, acc[jt], 0, 0, 0);
        }
    }
    __syncthreads();

    // Step C: O += P·V_ext
    short8 ap[2];
#pragma unroll
    for (int kt = 0; kt < 2; kt++) {
        int kg = kt * 4 + g;
        ap[kt] = *(const short8*)&sm[LK_ + mrow * 64 + (kg ^ (mrow & 7)) * 8];
    }
#pragma unroll
    for (int jt = 0; jt < 5; jt++) {
        int nrow = jt * 16 + fr;
#pragma unroll
        for (int kt = 0; kt < 2; kt++) {
            int kg = kt * 4 + g;
            short8 bvt = *(const short8*)&sm[LVT_ + nrow * 64 + (kg ^ (nrow & 7)) * 8];
            acc[jt] = __builtin_amdgcn_mfma_f32_16x16x32_bf16(ap[kt], bvt, acc[jt], 0, 0, 0);
        }
    }

    // denominator broadcast
    int srcl = g * 16;
    float rdi[4];
#pragma unroll
    for (int r = 0; r < 4; r++) {
        float den = __shfl(acc[4][r], srcl, 64);
        rdi[r] = 1.f / fmaxf(den, EPSV);
    }
    // O bf16 stage (stride 72 in LSP region)
#pragma unroll
    for (int jt = 0; jt < 4; jt++) {
        int e = jt * 16 + fr;
#pragma unroll
        for (int r = 0; r < 4; r++) {
            int t = wave * 16 + g * 4 + r;
            sm[LSP_ + t * 72 + e] = f2bf(acc[jt][r] * rdi[r]);
        }
    }
    __syncthreads();

#pragma unroll
    for (int it = 0; it < 2; it++) {
        int slot = it * 256 + tid;
        int row = slot >> 3, ch = slot & 7;
        ushort4 lo = *(const ushort4*)&sm[LSP_ + row * 72 + ch * 8];
        ushort4 hi = *(const ushort4*)&sm[LSP_ + row * 72 + ch * 8 + 4];
        ushort pk8[8] = {lo.x, lo.y, lo.z, lo.w, hi.x, hi.y, hi.z, hi.w};
        *(uint4*)&ob[(size_t)(b * TT + c * CC + row) * DD + h * DH + ch * 8] = *(uint4*)pk8;
    }
}

// ---------------------------------------------------------------------------
// Fused cooperative middle. __launch_bounds__(256,4): 4 waves/EU = 4 blocks/CU
// so the cooperative-occupancy check admits grid=1024.
// __threadfence() before sync = release (wbL2), after = acquire (invL2):
// cross-XCD L2s hold stale 0xAA-poison lines of Sb/SpT (G16).
// ---------------------------------------------------------------------------
__global__ __launch_bounds__(256, 4) void la_middle(
    const ushort* __restrict__ qkv, ushort* __restrict__ Sb,
    ushort* __restrict__ SpT, ushort* __restrict__ ob)
{
    cg::grid_group gridg = cg::this_grid();
    __shared__ __align__(16) ushort sm[18432];
    int blk = blockIdx.x;

    mid_phase1(qkv, Sb, blk, sm);
    __threadfence();
    gridg.sync();
    __threadfence();

    mid_phase2(Sb, SpT, blk);
    __threadfence();
    gridg.sync();
    __threadfence();

    mid_phase3<false>(qkv, SpT, ob, blk, sm);   // K rows + VT persist in LDS
}

// ---- fallback path: separate launches (kernel boundary = full coherence) ----
__global__ __launch_bounds__(256) void k_chunk(
    const ushort* __restrict__ qkv, ushort* __restrict__ Sb)
{
    __shared__ __align__(16) ushort sm[18432];
    mid_phase1(qkv, Sb, blockIdx.x, sm);
}

__global__ __launch_bounds__(256) void k_prefix(
    const ushort* __restrict__ Sb, ushort* __restrict__ SpT)
{
    mid_phase2(Sb, SpT, blockIdx.x);
}

__global__ __launch_bounds__(256) void k_attn(
    const ushort* __restrict__ qkv, const ushort* __restrict__ SpT,
    ushort* __restrict__ ob)
{
    __shared__ __align__(16) ushort sm[18432];
    mid_phase3<true>(qkv, SpT, ob, blockIdx.x, sm);
}

// ---------------------------------------------------------------------------
extern "C" void kernel_launch(void* const* d_in, const int* in_sizes, int n_in,
                              void* d_out, int out_size, void* d_ws, size_t ws_size,
                              hipStream_t stream) {
    const float* x  = (const float*)d_in[0];
    const float* Wq = (const float*)d_in[1];
    const float* bq = (const float*)d_in[2];
    const float* Wk = (const float*)d_in[3];
    const float* bk = (const float*)d_in[4];
    const float* Wv = (const float*)d_in[5];
    const float* bv = (const float*)d_in[6];
    const float* Wo = (const float*)d_in[7];
    const float* bo = (const float*)d_in[8];
    float* out = (float*)d_out;

    char* ws = (char*)d_ws;
    ushort* xb    = (ushort*)(ws + 0);          //  8388608 B
    ushort* Wqkvb = (ushort*)(ws + 8388608);    //  6291456 B
    ushort* Wob   = (ushort*)(ws + 14680064);   //  2097152 B
    float*  biasq = (float*)(ws + 16777216);    //    12288 B
    ushort* qkvb  = (ushort*)(ws + 16789504);   // 25165824 B (4096x3072 bf16)
    ushort* Sb    = (ushort*)(ws + 41955328);   // 10485760 B (1024x5120 bf16)
    ushort* SpTb  = (ushort*)(ws + 52441088);   // 10485760 B
    ushort* attnb = (ushort*)(ws + 0);          // reuse xb region

    convert_pack<<<4096, 256, 0, stream>>>(x, Wq, Wk, Wv, Wo, bq, bk, bv,
                                           xb, Wqkvb, Wob, biasq);
    // fused QKV projection -> bf16 (grid: m on x so XCD ties to m-tile)
    gemm_mfma<128, 128, true><<<dim3(BT / 128, 3072 / 128), 256, 0, stream>>>(
        xb, Wqkvb, biasq, qkvb, BT, 3072, DD, 2048);

    const ushort* qkv_p = qkvb;
    void* margs[] = {(void*)&qkv_p, (void*)&Sb, (void*)&SpTb, (void*)&attnb};
    hipError_t cerr = hipLaunchCooperativeKernel(
        (void*)la_middle, dim3(BB * HH * NC), dim3(256), margs, 0, stream);
    if (cerr != hipSuccess) {
        (void)hipGetLastError();   // clear sticky error, use separate kernels
        k_chunk<<<BB * HH * NC, 256, 0, stream>>>(qkvb, Sb);
        k_prefix<<<BB * HH * NC, 256, 0, stream>>>(Sb, SpTb);
        k_attn<<<BB * HH * NC, 256, 0, stream>>>(qkvb, SpTb, attnb);
    }

    gemm_mfma<64, 128, false><<<dim3(BT / 64, DD / 128), 256, 0, stream>>>(
        attnb, Wob, bo, out, BT, DD, DD, 0);
}

// Round 9
// 161.580 us; speedup vs baseline: 4.5971x; 4.5971x over previous
//
#include <hip/hip_runtime.h>
#include <math.h>

// Problem constants
#define BB 2
#define TT 2048
#define DD 1024
#define HH 16
#define DH 64
#define BT (BB*TT)          // 4096
#define CC 64               // chunk length
#define NC (TT/CC)          // 32 chunks
#define EPSV 1e-6f
#define QS 3072             // fused qkv row stride (bf16)

typedef __attribute__((ext_vector_type(8))) short short8;
typedef __attribute__((ext_vector_type(4))) float f32x4;

__device__ inline ushort f2bf(float f) {
    unsigned u = __float_as_uint(f);
    u = (u + 0x7fffu + ((u >> 16) & 1u)) >> 16;   // RNE
    return (ushort)u;
}
__device__ inline float bf2f(ushort u) {
    return __uint_as_float(((unsigned)u) << 16);
}

__device__ inline void async16(const void* g, void* l) {
    __builtin_amdgcn_global_load_lds(
        (const __attribute__((address_space(1))) void*)g,
        (__attribute__((address_space(3))) void*)l, 16, 0, 0);
}

// ---------------------------------------------------------------------------
// Pack fp32 -> bf16: xb (4M), Wqkvb = [Wq;Wk;Wv] (3M), Wob (1M); biasq fp32.
// ---------------------------------------------------------------------------
__global__ __launch_bounds__(256) void convert_pack(
    const float* __restrict__ x, const float* __restrict__ Wq,
    const float* __restrict__ Wk, const float* __restrict__ Wv,
    const float* __restrict__ Wo, const float* __restrict__ bq,
    const float* __restrict__ bk, const float* __restrict__ bv,
    ushort* __restrict__ xb, ushort* __restrict__ Wqkvb,
    ushort* __restrict__ Wob, float* __restrict__ biasq)
{
    int i = blockIdx.x * 256 + threadIdx.x;      // 0..1048575
    int idx = i * 8;
    const float* src;
    ushort* dst;
    if (idx < 4194304) { src = x + idx; dst = xb + idx; }
    else if (idx < 7340032) {
        int r = idx - 4194304;
        int w = r >> 20;
        int o = r & 1048575;
        src = (w == 0 ? Wq : (w == 1 ? Wk : Wv)) + o;
        dst = Wqkvb + r;
    } else {
        int r = idx - 7340032;
        src = Wo + r; dst = Wob + r;
    }
    float4 f0 = *(const float4*)src;
    float4 f1 = *(const float4*)(src + 4);
    *(ushort4*)dst = make_ushort4(f2bf(f0.x), f2bf(f0.y), f2bf(f0.z), f2bf(f0.w));
    *(ushort4*)(dst + 4) = make_ushort4(f2bf(f1.x), f2bf(f1.y), f2bf(f1.z), f2bf(f1.w));
    if (i < 3072)
        biasq[i] = (i < 1024) ? bq[i] : (i < 2048) ? bk[i - 1024] : bv[i - 2048];
}

// ---------------------------------------------------------------------------
// MFMA bf16 GEMM, BK=64: C = act(A·Wᵀ + bias).
// m-tile on blockIdx.x so blk%8 (XCD) ties to m -> activation rows L2-local.
// OBF16: bf16 out via LDS transpose; else fp32 out via LDS-staged float4.
// ---------------------------------------------------------------------------
template<int TBM, int TBN, bool OBF16>
__global__ __launch_bounds__(256) void gemm_mfma(
    const ushort* __restrict__ A, const ushort* __restrict__ W,
    const float* __restrict__ bias, void* __restrict__ Cv,
    int M, int N, int K, int act_limit)
{
    constexpr int IT = TBM / 32, JT = TBN / 32;
    constexpr int APT = TBM * 8 / 256;
    constexpr int BPT = TBN * 8 / 256;
    constexpr int STAGE_US = (TBM + TBN) * 64;
    constexpr int EPI_US = OBF16 ? TBM * 132 : TBM * 264;
    constexpr int SMEM_US = (EPI_US > STAGE_US) ? EPI_US : STAGE_US;
    __shared__ __align__(16) ushort smem[SMEM_US];
    ushort* As = smem;
    ushort* Bs = smem + TBM * 64;
    int tid = threadIdx.x;
    int lane = tid & 63, wave = tid >> 6;
    int m0 = blockIdx.x * TBM, n0 = blockIdx.y * TBN;
    int wm = (wave >> 1) * (TBM / 2), wn = (wave & 1) * (TBN / 2);

    const ushort* gA[APT]; ushort* lA[APT];
    const ushort* gB[BPT]; ushort* lB[BPT];
#pragma unroll
    for (int s = 0; s < APT; s++) {
        int slot = s * 256 + tid;
        int row = slot >> 3, p = slot & 7, kg = p ^ (row & 7);
        gA[s] = A + (size_t)(m0 + row) * K + kg * 8;
        lA[s] = &As[slot * 8];
    }
#pragma unroll
    for (int s = 0; s < BPT; s++) {
        int slot = s * 256 + tid;
        int row = slot >> 3, p = slot & 7, kg = p ^ (row & 7);
        gB[s] = W + (size_t)(n0 + row) * K + kg * 8;
        lB[s] = &Bs[slot * 8];
    }

    int fr = lane & 15, g = lane >> 4;

    f32x4 acc[IT][JT];
#pragma unroll
    for (int i = 0; i < IT; i++)
#pragma unroll
        for (int j = 0; j < JT; j++) acc[i][j] = (f32x4){0.f, 0.f, 0.f, 0.f};

    for (int kt = 0; kt < K; kt += 64) {
#pragma unroll
        for (int s = 0; s < APT; s++) async16(gA[s] + kt, lA[s]);
#pragma unroll
        for (int s = 0; s < BPT; s++) async16(gB[s] + kt, lB[s]);
        __syncthreads();
#pragma unroll
        for (int ks = 0; ks < 2; ks++) {
            int kg = ks * 4 + g;
            short8 af[IT], bf[JT];
#pragma unroll
            for (int i = 0; i < IT; i++) {
                int mr = wm + i * 16 + fr;
                af[i] = *(const short8*)&As[mr * 64 + (kg ^ (mr & 7)) * 8];
            }
#pragma unroll
            for (int j = 0; j < JT; j++) {
                int nr = wn + j * 16 + fr;
                bf[j] = *(const short8*)&Bs[nr * 64 + (kg ^ (nr & 7)) * 8];
            }
#pragma unroll
            for (int i = 0; i < IT; i++)
#pragma unroll
                for (int j = 0; j < JT; j++)
                    acc[i][j] = __builtin_amdgcn_mfma_f32_16x16x32_bf16(
                        af[i], bf[j], acc[i][j], 0, 0, 0);
        }
        __syncthreads();
    }

    // epilogue: C/D layout col=lane&15, row=(lane>>4)*4+reg
    if (OBF16) {
        ushort* Cs = smem;   // TBM x 132
#pragma unroll
        for (int j = 0; j < JT; j++) {
            int colL = wn + j * 16 + fr;
            float bv_ = bias[n0 + colL];
            bool act = (n0 + colL) < act_limit;
#pragma unroll
            for (int i = 0; i < IT; i++) {
                int rowL = wm + i * 16 + g * 4;
#pragma unroll
                for (int r = 0; r < 4; r++) {
                    float v = acc[i][j][r] + bv_;
                    if (act) v = (v > 0.f) ? (v + 1.f) : expf(v);
                    Cs[(rowL + r) * 132 + colL] = f2bf(v);
                }
            }
        }
        __syncthreads();
        ushort* C = (ushort*)Cv;
        int orow = tid >> 4, ocol = (tid & 15) * 8;
#pragma unroll
        for (int it = 0; it < TBM / 16; it++) {
            int rr = orow + it * 16;
            ushort4 lo = *(const ushort4*)&Cs[rr * 132 + ocol];
            ushort4 hi = *(const ushort4*)&Cs[rr * 132 + ocol + 4];
            ushort pk8[8] = {lo.x, lo.y, lo.z, lo.w, hi.x, hi.y, hi.z, hi.w};
            *(uint4*)&C[(size_t)(m0 + rr) * N + n0 + ocol] = *(uint4*)pk8;
        }
    } else {
        float* Cs = (float*)smem;   // TBM x 132 fp32
#pragma unroll
        for (int j = 0; j < JT; j++) {
            int colL = wn + j * 16 + fr;
            float bv_ = bias[n0 + colL];
            bool act = (n0 + colL) < act_limit;
#pragma unroll
            for (int i = 0; i < IT; i++) {
                int rowL = wm + i * 16 + g * 4;
#pragma unroll
                for (int r = 0; r < 4; r++) {
                    float v = acc[i][j][r] + bv_;
                    if (act) v = (v > 0.f) ? (v + 1.f) : expf(v);
                    Cs[(rowL + r) * 132 + colL] = v;
                }
            }
        }
        __syncthreads();
        float* C = (float*)Cv;
#pragma unroll
        for (int it = 0; it < TBM * TBN / 1024; it++) {
            int slot = it * 256 + tid;
            int row = slot / (TBN / 4), c4 = slot % (TBN / 4);
            float4 v4 = *(const float4*)&Cs[row * 132 + c4 * 4];
            *(float4*)&C[(size_t)(m0 + row) * N + n0 + c4 * 4] = v4;
        }
    }
}

// ===========================================================================
// Middle phase bodies (verified math from round 8). LDS (ushort idx):
// R0 @0: KT ph1 / Q ph3. R1 @4096: K rows / P. R2 @8192 (5120): SpT then
// O-stage. R3 @13312 (5120): VT. 8-quad XOR swizzle throughout.
// ===========================================================================
#define LQ_ 0
#define LK_ 4096
#define LSP_ 8192
#define LVT_ 13312

__device__ __forceinline__ void mid_phase1(
    const ushort* __restrict__ qkv, ushort* __restrict__ Sb,
    int blk, ushort* sm)
{
    int tid = threadIdx.x, lane = tid & 63, wave = tid >> 6;
    int c = blk & (NC - 1);
    int bh = blk >> 5;
    int b = bh >> 4, h = bh & 15;
    size_t rowbase = (size_t)(b * TT + c * CC) * QS + h * DH;
    int fr = lane & 15, g = lane >> 4;

    // KT + VT (scatter, swizzled)
    {
        int rrow = tid >> 4, rc4 = (tid & 15) * 4;
#pragma unroll
        for (int r = 0; r < 4; r++) {
            int row = rrow + r * 16;
            ushort4 k4 = *(const ushort4*)&qkv[rowbase + (size_t)row * QS + 1024 + rc4];
            ushort4 v4 = *(const ushort4*)&qkv[rowbase + (size_t)row * QS + 2048 + rc4];
#pragma unroll
            for (int j = 0; j < 4; j++) {
                int d = rc4 + j;
                int pos = (row >> 3) ^ (d & 7);
                sm[LQ_  + d * 64 + pos * 8 + (row & 7)] = ((const ushort*)&k4)[j];
                sm[LVT_ + d * 64 + pos * 8 + (row & 7)] = ((const ushort*)&v4)[j];
            }
        }
        if (tid < 16) {   // ones row e=64 of VT
            ushort4 one4 = make_ushort4(0x3F80, 0x3F80, 0x3F80, 0x3F80);
            *(ushort4*)&sm[LVT_ + 64 * 64 + tid * 4] = one4;
        }
    }
    __syncthreads();

    // Sᵀ_ext[e][d] = Σ_t V_ext[t][e]·K[t][d]
    short8 bk_[2];
#pragma unroll
    for (int kt = 0; kt < 2; kt++) {
        int row = wave * 16 + fr;
        int kg = kt * 4 + g;
        bk_[kt] = *(const short8*)&sm[LQ_ + row * 64 + (kg ^ (row & 7)) * 8];
    }
    f32x4 accS[5];
#pragma unroll
    for (int it = 0; it < 5; it++) accS[it] = (f32x4){0.f, 0.f, 0.f, 0.f};
#pragma unroll
    for (int it = 0; it < 5; it++) {
        int arow = it * 16 + fr;
#pragma unroll
        for (int kt = 0; kt < 2; kt++) {
            int kg = kt * 4 + g;
            short8 av = *(const short8*)&sm[LVT_ + arow * 64 + (kg ^ (arow & 7)) * 8];
            accS[it] = __builtin_amdgcn_mfma_f32_16x16x32_bf16(av, bk_[kt], accS[it], 0, 0, 0);
        }
    }
    size_t sb = (size_t)blk * 5120;
#pragma unroll
    for (int it = 0; it < 4; it++)
#pragma unroll
        for (int r = 0; r < 4; r++) {
            int e = it * 16 + g * 4 + r;
            Sb[sb + e * 64 + wave * 16 + fr] = f2bf(accS[it][r]);
        }
    if (g == 0) Sb[sb + 64 * 64 + wave * 16 + fr] = f2bf(accS[4][0]);
}

__device__ __forceinline__ void mid_phase2(
    const ushort* __restrict__ Sb, ushort* __restrict__ SpT, int blk)
{
    int tid = threadIdx.x;
    int pbh = blk >> 5, seg = blk & 31;       // 32 bh x 32 segs of 160
    size_t base = (size_t)pbh * NC * 5120;
    if (tid >= 160) return;
    int idx = seg * 160 + tid;                // 0..5119
    int e = idx >> 6, d = idx & 63;
    int pos = (d >> 3) ^ (e & 7);
    size_t woff = (size_t)e * 64 + pos * 8 + (d & 7);
    if (e <= 64) {
        float run = 0.f;
        for (int cc = 0; cc < NC; cc++) {
            size_t boff = base + (size_t)cc * 5120;
            float t = bf2f(Sb[boff + idx]);
            SpT[boff + woff] = f2bf(run);
            run += t;
        }
    } else {
        for (int cc = 0; cc < NC; cc++)
            SpT[base + (size_t)cc * 5120 + woff] = 0;
    }
}

__device__ __forceinline__ void mid_phase3(
    const ushort* __restrict__ qkv, const ushort* __restrict__ SpT,
    ushort* __restrict__ ob, int blk, ushort* sm)
{
    int tid = threadIdx.x, lane = tid & 63, wave = tid >> 6;
    int c = blk & (NC - 1);
    int bh = blk >> 5;
    int b = bh >> 4, h = bh & 15;
    size_t rowbase = (size_t)(b * TT + c * CC) * QS + h * DH;
    int fr = lane & 15, g = lane >> 4;

    // stage Q + K rows (async, swizzled)
#pragma unroll
    for (int r = 0; r < 2; r++) {
        int slot = (r * 4 + wave) * 64 + lane;
        int row = slot >> 3, p = slot & 7;
        int kg = p ^ (row & 7);
        const ushort* gq = qkv + rowbase + (size_t)row * QS + kg * 8;
        async16(gq, &sm[LQ_ + slot * 8]);
        async16(gq + 1024, &sm[LK_ + slot * 8]);
    }
    // stage SpT (pre-swizzled in global): flat copy, 640 slots
    {
        size_t spbase = (size_t)blk * 5120;
        int slot = wave * 64 + lane;
        async16(SpT + spbase + slot * 8, &sm[LSP_ + slot * 8]);
        async16(SpT + spbase + (slot + 256) * 8, &sm[LSP_ + (slot + 256) * 8]);
        if (wave < 2) {
            int s2 = 512 + wave * 64 + lane;
            async16(SpT + spbase + s2 * 8, &sm[LSP_ + s2 * 8]);
        }
    }
    // stage V transposed (scatter)
    {
        int rrow = tid >> 4, rc4 = (tid & 15) * 4;
#pragma unroll
        for (int r = 0; r < 4; r++) {
            int row = rrow + r * 16;
            ushort4 v4 = *(const ushort4*)&qkv[rowbase + (size_t)row * QS + 2048 + rc4];
#pragma unroll
            for (int j = 0; j < 4; j++) {
                int e = rc4 + j;
                int pos = (row >> 3) ^ (e & 7);
                sm[LVT_ + e * 64 + pos * 8 + (row & 7)] = ((const ushort*)&v4)[j];
            }
        }
        if (tid < 16) {
            ushort4 one4 = make_ushort4(0x3F80, 0x3F80, 0x3F80, 0x3F80);
            *(ushort4*)&sm[LVT_ + 64 * 64 + tid * 4] = one4;
        }
    }
    __syncthreads();

    int mrow = wave * 16 + fr;
    short8 aq[2];
#pragma unroll
    for (int kt = 0; kt < 2; kt++) {
        int kg = kt * 4 + g;
        aq[kt] = *(const short8*)&sm[LQ_ + mrow * 64 + (kg ^ (mrow & 7)) * 8];
    }

    // Step A: A = Q·Kᵀ
    f32x4 accA[4];
#pragma unroll
    for (int jt = 0; jt < 4; jt++) accA[jt] = (f32x4){0.f, 0.f, 0.f, 0.f};
#pragma unroll
    for (int jt = 0; jt < 4; jt++) {
        int nrow = jt * 16 + fr;
#pragma unroll
        for (int kt = 0; kt < 2; kt++) {
            int kg = kt * 4 + g;
            short8 bk_ = *(const short8*)&sm[LK_ + nrow * 64 + (kg ^ (nrow & 7)) * 8];
            accA[jt] = __builtin_amdgcn_mfma_f32_16x16x32_bf16(aq[kt], bk_, accA[jt], 0, 0, 0);
        }
    }
    __syncthreads();

    // mask -> P (bf16) into LK region
#pragma unroll
    for (int jt = 0; jt < 4; jt++) {
        int s = jt * 16 + fr;
#pragma unroll
        for (int r = 0; r < 4; r++) {
            int t = wave * 16 + g * 4 + r;
            float pv = (s <= t) ? accA[jt][r] : 0.f;
            int pos = (s >> 3) ^ (t & 7);
            sm[LK_ + t * 64 + pos * 8 + (s & 7)] = f2bf(pv);
        }
    }

    // Step B: O += Q·Sp_ext
    f32x4 acc[5];
#pragma unroll
    for (int jt = 0; jt < 5; jt++) acc[jt] = (f32x4){0.f, 0.f, 0.f, 0.f};
#pragma unroll
    for (int jt = 0; jt < 5; jt++) {
        int nrow = jt * 16 + fr;
#pragma unroll
        for (int kt = 0; kt < 2; kt++) {
            int kg = kt * 4 + g;
            short8 bsp = *(const short8*)&sm[LSP_ + nrow * 64 + (kg ^ (nrow & 7)) * 8];
            acc[jt] = __builtin_amdgcn_mfma_f32_16x16x32_bf16(aq[kt], bsp, acc[jt], 0, 0, 0);
        }
    }
    __syncthreads();

    // Step C: O += P·V_ext
    short8 ap[2];
#pragma unroll
    for (int kt = 0; kt < 2; kt++) {
        int kg = kt * 4 + g;
        ap[kt] = *(const short8*)&sm[LK_ + mrow * 64 + (kg ^ (mrow & 7)) * 8];
    }
#pragma unroll
    for (int jt = 0; jt < 5; jt++) {
        int nrow = jt * 16 + fr;
#pragma unroll
        for (int kt = 0; kt < 2; kt++) {
            int kg = kt * 4 + g;
            short8 bvt = *(const short8*)&sm[LVT_ + nrow * 64 + (kg ^ (nrow & 7)) * 8];
            acc[jt] = __builtin_amdgcn_mfma_f32_16x16x32_bf16(ap[kt], bvt, acc[jt], 0, 0, 0);
        }
    }

    // denominator broadcast
    int srcl = g * 16;
    float rdi[4];
#pragma unroll
    for (int r = 0; r < 4; r++) {
        float den = __shfl(acc[4][r], srcl, 64);
        rdi[r] = 1.f / fmaxf(den, EPSV);
    }
    // O bf16 stage (stride 72 in LSP region)
#pragma unroll
    for (int jt = 0; jt < 4; jt++) {
        int e = jt * 16 + fr;
#pragma unroll
        for (int r = 0; r < 4; r++) {
            int t = wave * 16 + g * 4 + r;
            sm[LSP_ + t * 72 + e] = f2bf(acc[jt][r] * rdi[r]);
        }
    }
    __syncthreads();

#pragma unroll
    for (int it = 0; it < 2; it++) {
        int slot = it * 256 + tid;
        int row = slot >> 3, ch = slot & 7;
        ushort4 lo = *(const ushort4*)&sm[LSP_ + row * 72 + ch * 8];
        ushort4 hi = *(const ushort4*)&sm[LSP_ + row * 72 + ch * 8 + 4];
        ushort pk8[8] = {lo.x, lo.y, lo.z, lo.w, hi.x, hi.y, hi.z, hi.w};
        *(uint4*)&ob[(size_t)(b * TT + c * CC + row) * DD + h * DH + ch * 8] = *(uint4*)pk8;
    }
}

// ---- middle kernels (kernel boundary = cheap grid barrier + coherence) ----
__global__ __launch_bounds__(256) void k_chunk(
    const ushort* __restrict__ qkv, ushort* __restrict__ Sb)
{
    __shared__ __align__(16) ushort sm[18432];
    mid_phase1(qkv, Sb, blockIdx.x, sm);
}

__global__ __launch_bounds__(256) void k_prefix(
    const ushort* __restrict__ Sb, ushort* __restrict__ SpT)
{
    mid_phase2(Sb, SpT, blockIdx.x);
}

__global__ __launch_bounds__(256) void k_attn(
    const ushort* __restrict__ qkv, const ushort* __restrict__ SpT,
    ushort* __restrict__ ob)
{
    __shared__ __align__(16) ushort sm[18432];
    mid_phase3(qkv, SpT, ob, blockIdx.x, sm);
}

// ---------------------------------------------------------------------------
extern "C" void kernel_launch(void* const* d_in, const int* in_sizes, int n_in,
                              void* d_out, int out_size, void* d_ws, size_t ws_size,
                              hipStream_t stream) {
    const float* x  = (const float*)d_in[0];
    const float* Wq = (const float*)d_in[1];
    const float* bq = (const float*)d_in[2];
    const float* Wk = (const float*)d_in[3];
    const float* bk = (const float*)d_in[4];
    const float* Wv = (const float*)d_in[5];
    const float* bv = (const float*)d_in[6];
    const float* Wo = (const float*)d_in[7];
    const float* bo = (const float*)d_in[8];
    float* out = (float*)d_out;

    char* ws = (char*)d_ws;
    ushort* xb    = (ushort*)(ws + 0);          //  8388608 B
    ushort* Wqkvb = (ushort*)(ws + 8388608);    //  6291456 B
    ushort* Wob   = (ushort*)(ws + 14680064);   //  2097152 B
    float*  biasq = (float*)(ws + 16777216);    //    12288 B
    ushort* qkvb  = (ushort*)(ws + 16789504);   // 25165824 B (4096x3072 bf16)
    ushort* Sb    = (ushort*)(ws + 41955328);   // 10485760 B (1024x5120 bf16)
    ushort* SpTb  = (ushort*)(ws + 52441088);   // 10485760 B
    ushort* attnb = (ushort*)(ws + 0);          // reuse xb region

    convert_pack<<<4096, 256, 0, stream>>>(x, Wq, Wk, Wv, Wo, bq, bk, bv,
                                           xb, Wqkvb, Wob, biasq);
    // fused QKV projection -> bf16 (grid: m on x so XCD ties to m-tile)
    gemm_mfma<128, 128, true><<<dim3(BT / 128, 3072 / 128), 256, 0, stream>>>(
        xb, Wqkvb, biasq, qkvb, BT, 3072, DD, 2048);

    k_chunk<<<BB * HH * NC, 256, 0, stream>>>(qkvb, Sb);
    k_prefix<<<BB * HH * NC, 256, 0, stream>>>(Sb, SpTb);
    k_attn<<<BB * HH * NC, 256, 0, stream>>>(qkvb, SpTb, attnb);

    gemm_mfma<64, 128, false><<<dim3(BT / 64, DD / 128), 256, 0, stream>>>(
        attnb, Wob, bo, out, BT, DD, DD, 0);
}